// Round 5
// baseline (197.173 us; speedup 1.0000x reference)
//
#include <hip/hip_runtime.h>

#define EPS 1e-6f

constexpr int C      = 128;
constexpr int HW     = 65536;   // 256*256
constexpr int TILE   = 128;     // pixels per tile
constexpr int NT     = 512;     // 8 waves
constexpr int NTILES = 8;       // tiles per block (pipelined)

typedef __attribute__((ext_vector_type(8))) short bf16x8;
typedef __attribute__((ext_vector_type(4))) float f32x4;

__device__ __forceinline__ unsigned short f2bf(float f) {   // RNE
    unsigned u = __float_as_uint(f);
    u += 0x7fff + ((u >> 16) & 1);
    return (unsigned short)(u >> 16);
}
__device__ __forceinline__ float bf2f(unsigned short u) {
    return __uint_as_float(((unsigned)u) << 16);
}
__device__ __forceinline__ unsigned pack2(float lo, float hi) {
    return (unsigned)f2bf(lo) | ((unsigned)f2bf(hi) << 16);
}

// raw barrier: does NOT drain vmcnt (keeps global prefetch in flight),
// but drains LDS ops so cross-thread LDS producer/consumer is safe.
#define BAR() do { \
    asm volatile("s_waitcnt lgkmcnt(0)" ::: "memory"); \
    __builtin_amdgcn_s_barrier(); \
    __builtin_amdgcn_sched_barrier(0); \
} while (0)

__global__ __launch_bounds__(NT, 4) void spnorm_kernel(
    const float* __restrict__ x, const float* __restrict__ W,
    const float* __restrict__ bias, float* __restrict__ out)
{
    __shared__ unsigned short bufN[C * TILE];              // 32 KB raw bf16 stage
    __shared__ unsigned short bufT[C * TILE];              // 32 KB normalized, transposed, swizzled
    __shared__ float red1[4][TILE], red2[4][TILE];         // 4 KB
    __shared__ float u_s[TILE], iv_s[TILE], se_s[TILE];    // 1.5 KB

    const int tid = threadIdx.x;
    const int l   = tid & 63;
    const int wv  = tid >> 6;

    const int blkPerImg = HW / (TILE * NTILES);            // 64
    const int batch = blockIdx.x / blkPerImg;
    const int hw0   = (blockIdx.x % blkPerImg) * (TILE * NTILES);
    const int ibase = batch * (C * HW) + hw0;              // start of this block's pixel run

    // staging map: thread covers channels c = it*16 + sc, pixels sp4..sp4+3
    const int sc  = tid >> 5;
    const int sp4 = (tid & 31) << 2;
    // stats map
    const int p = tid & 127;
    const int q = tid >> 7;

    // ---- A-fragments: W (fp32 -> bf16), persistent across tiles ----
    const int arow  = (wv << 4) + (l & 15);
    const int acol0 = (l >> 4) << 3;
    bf16x8 afrag[4];
    #pragma unroll
    for (int kk = 0; kk < 4; ++kk) {
        const float* wp = W + arow * C + kk * 32 + acol0;
        float4 wa = *reinterpret_cast<const float4*>(wp);
        float4 wb = *reinterpret_cast<const float4*>(wp + 4);
        bf16x8 f;
        f[0] = (short)f2bf(wa.x); f[1] = (short)f2bf(wa.y);
        f[2] = (short)f2bf(wa.z); f[3] = (short)f2bf(wa.w);
        f[4] = (short)f2bf(wb.x); f[5] = (short)f2bf(wb.y);
        f[6] = (short)f2bf(wb.z); f[7] = (short)f2bf(wb.w);
        afrag[kk] = f;
    }
    const int od = (wv << 4) + ((l >> 4) << 2);
    const f32x4 binit = { bias[od], bias[od + 1], bias[od + 2], bias[od + 3] };

    // ---- prologue: stage tile 0 into bufN ----
    {
        const float* xb = x + ibase;
        #pragma unroll
        for (int it = 0; it < 8; ++it) {
            float4 v = *reinterpret_cast<const float4*>(xb + (it * 16 + sc) * HW + sp4);
            uint2 d;
            d.x = pack2(v.x, v.y);
            d.y = pack2(v.z, v.w);
            *reinterpret_cast<uint2*>(&bufN[(it * 16 + sc) * TILE + sp4]) = d;
        }
    }
    BAR();

    for (int t = 0; t < NTILES; ++t) {
        // ---- issue next tile's global loads (stay in flight across the iteration) ----
        float4 pf[8];
        if (t + 1 < NTILES) {
            const float* xb = x + ibase + (t + 1) * TILE;
            #pragma unroll
            for (int it = 0; it < 8; ++it)
                pf[it] = *reinterpret_cast<const float4*>(xb + (it * 16 + sc) * HW + sp4);
        }

        // ---- stats: cache column in regs, partial sums ----
        float v[32];
        {
            float s1 = 0.f, s2 = 0.f;
            #pragma unroll
            for (int i = 0; i < 32; ++i) {
                float tv = bf2f(bufN[(q * 32 + i) * TILE + p]);
                v[i] = tv;
                s1 += tv;
                s2 = fmaf(tv, tv, s2);
            }
            red1[q][p] = s1;
            red2[q][p] = s2;
        }
        BAR();
        if (tid < TILE) {
            float s1 = red1[0][tid] + red1[1][tid] + red1[2][tid] + red1[3][tid];
            float s2 = red2[0][tid] + red2[1][tid] + red2[2][tid] + red2[3][tid];
            float u   = s1 * (1.0f / 128.0f);
            float var = fmaxf((s2 - s1 * u) * (1.0f / 127.0f), 0.0f);
            float se  = sqrtf(var) + EPS;
            u_s[tid]  = u;
            se_s[tid] = se;
            iv_s[tid] = 1.0f / se;
        }
        BAR();

        // ---- normalize regs -> bufT (transposed, XOR-swizzled rows) ----
        {
            char* tb = (char*)bufT;
            const float u  = u_s[p];
            const float iv = iv_s[p];
            const int rowoff = p * 256;
            const int swz    = (p & 15) << 4;
            #pragma unroll
            for (int o8 = 0; o8 < 4; ++o8) {
                float n0 = (v[o8 * 8 + 0] - u) * iv;
                float n1 = (v[o8 * 8 + 1] - u) * iv;
                float n2 = (v[o8 * 8 + 2] - u) * iv;
                float n3 = (v[o8 * 8 + 3] - u) * iv;
                float n4 = (v[o8 * 8 + 4] - u) * iv;
                float n5 = (v[o8 * 8 + 5] - u) * iv;
                float n6 = (v[o8 * 8 + 6] - u) * iv;
                float n7 = (v[o8 * 8 + 7] - u) * iv;
                uint4 d;
                d.x = pack2(n0, n1);
                d.y = pack2(n2, n3);
                d.z = pack2(n4, n5);
                d.w = pack2(n6, n7);
                int byte = (rowoff + (q * 4 + o8) * 16) ^ swz;
                *reinterpret_cast<uint4*>(tb + byte) = d;
            }
        }

        // ---- stage next tile into bufN (bufN(t) fully consumed by stats) ----
        if (t + 1 < NTILES) {
            #pragma unroll
            for (int it = 0; it < 8; ++it) {
                uint2 d;
                d.x = pack2(pf[it].x, pf[it].y);
                d.y = pack2(pf[it].z, pf[it].w);
                *reinterpret_cast<uint2*>(&bufN[(it * 16 + sc) * TILE + sp4]) = d;
            }
        }
        BAR();

        // ---- MFMA conv + epilogue (reads bufT); no trailing barrier needed ----
        {
            const char* tb = (const char*)bufT;
            const int pcol = l & 15;
            const int koff = (l >> 4) << 4;
            const int swz  = pcol << 4;
            float* outp = out + ibase + t * TILE;
            #pragma unroll
            for (int pt = 0; pt < 8; ++pt) {
                const int pp     = (pt << 4) + pcol;
                const int rowoff = pp * 256;
                f32x4 acc = binit;
                #pragma unroll
                for (int kk = 0; kk < 4; ++kk) {
                    int byte = (rowoff + kk * 64 + koff) ^ swz;
                    bf16x8 bfrag = *reinterpret_cast<const bf16x8*>(tb + byte);
                    acc = __builtin_amdgcn_mfma_f32_16x16x32_bf16(afrag[kk], bfrag, acc, 0, 0, 0);
                }
                const float uu = u_s[pp];
                const float se = se_s[pp];
                int nbyte = (rowoff + od * 2) ^ swz;
                uint2 nn = *reinterpret_cast<const uint2*>(tb + nbyte);
                float x0 = fmaf(bf2f((unsigned short)(nn.x & 0xffffu)), se, uu);
                float x1 = fmaf(bf2f((unsigned short)(nn.x >> 16)),     se, uu);
                float x2 = fmaf(bf2f((unsigned short)(nn.y & 0xffffu)), se, uu);
                float x3 = fmaf(bf2f((unsigned short)(nn.y >> 16)),     se, uu);
                outp[(od + 0) * HW + pp] = x0 * acc[0];
                outp[(od + 1) * HW + pp] = x1 * acc[1];
                outp[(od + 2) * HW + pp] = x2 * acc[2];
                outp[(od + 3) * HW + pp] = x3 * acc[3];
            }
        }
        // Safe without a barrier here: next iteration's first LDS writes (red)
        // are disjoint from bufT/u_s reads above, and its bufT/bufN writes sit
        // behind the post-stats barrier, by which time all waves left this phase.
    }
}

extern "C" void kernel_launch(void* const* d_in, const int* in_sizes, int n_in,
                              void* d_out, int out_size, void* d_ws, size_t ws_size,
                              hipStream_t stream) {
    const float* x = (const float*)d_in[0];
    const float* W = (const float*)d_in[1];
    const float* b = (const float*)d_in[2];
    float* out     = (float*)d_out;

    const int nblk = 8 * HW / (TILE * NTILES);     // 512 blocks = 2 per CU, one round
    spnorm_kernel<<<nblk, NT, 0, stream>>>(x, W, b, out);
}

// Round 6
// 121.340 us; speedup vs baseline: 1.6250x; 1.6250x over previous
//
#include <hip/hip_runtime.h>

#define EPS 1e-6f

constexpr int C    = 128;
constexpr int HW   = 65536;    // 256*256
constexpr int TILE = 128;      // pixels per block
constexpr int NT   = 512;      // 8 waves

typedef __attribute__((ext_vector_type(8))) short bf16x8;
typedef __attribute__((ext_vector_type(4))) float f32x4;

__device__ __forceinline__ unsigned short f2bf(float f) {   // RNE
    unsigned u = __float_as_uint(f);
    u += 0x7fff + ((u >> 16) & 1);
    return (unsigned short)(u >> 16);
}
__device__ __forceinline__ float bf2f(unsigned short u) {
    return __uint_as_float(((unsigned)u) << 16);
}
__device__ __forceinline__ unsigned pack2(float lo, float hi) {
    return (unsigned)f2bf(lo) | ((unsigned)f2bf(hi) << 16);
}

__global__ __launch_bounds__(NT, 4) void spnorm_kernel(
    const float* __restrict__ x, const float* __restrict__ W,
    const float* __restrict__ bias, float* __restrict__ out)
{
    // bufT[p][c]: normalized bf16, transposed, XOR-swizzled (byte ^= (p&15)<<4)
    __shared__ unsigned short bufT[C * TILE];              // 32 KB
    __shared__ float red1[4][TILE], red2[4][TILE];         // 4 KB
    __shared__ float u_s[TILE], se_s[TILE];                // 1 KB

    const int tid = threadIdx.x;
    const int l   = tid & 63;
    const int wv  = tid >> 6;
    const int batch = blockIdx.x >> 9;                     // 512 blocks per image
    const int hw0   = (blockIdx.x & 511) * TILE;
    const int base  = batch * (C * HW) + hw0;

    const int p = tid & 127;                               // pixel
    const int q = tid >> 7;                                // channel group (32 ch)

    // ---- Phase 1: x straight into registers, channel-strided, coalesced across p ----
    float v[32];
    {
        const float* xp = x + base + q * 32 * HW + p;
        #pragma unroll
        for (int i = 0; i < 32; ++i)
            v[i] = xp[i * HW];
    }

    // ---- A-fragments: W (fp32 -> bf16) from global; persistent ----
    const int arow  = (wv << 4) + (l & 15);
    const int acol0 = (l >> 4) << 3;
    bf16x8 afrag[4];
    #pragma unroll
    for (int kk = 0; kk < 4; ++kk) {
        const float* wp = W + arow * C + kk * 32 + acol0;
        float4 wa = *reinterpret_cast<const float4*>(wp);
        float4 wb = *reinterpret_cast<const float4*>(wp + 4);
        bf16x8 f;
        f[0] = (short)f2bf(wa.x); f[1] = (short)f2bf(wa.y);
        f[2] = (short)f2bf(wa.z); f[3] = (short)f2bf(wa.w);
        f[4] = (short)f2bf(wb.x); f[5] = (short)f2bf(wb.y);
        f[6] = (short)f2bf(wb.z); f[7] = (short)f2bf(wb.w);
        afrag[kk] = f;
    }
    const int od = (wv << 4) + ((l >> 4) << 2);
    const f32x4 binit = { bias[od], bias[od + 1], bias[od + 2], bias[od + 3] };

    // ---- Phase 2: partial sums -> LDS ----
    {
        float s1 = 0.f, s2 = 0.f;
        #pragma unroll
        for (int i = 0; i < 32; ++i) {
            s1 += v[i];
            s2 = fmaf(v[i], v[i], s2);
        }
        red1[q][p] = s1;
        red2[q][p] = s2;
    }
    __syncthreads();

    // ---- Phase 3: every thread finalizes (redundant x4, no divergence barrier),
    //      normalizes its 32 regs, writes bufT transposed+swizzled ----
    {
        float s1 = red1[0][p] + red1[1][p] + red1[2][p] + red1[3][p];
        float s2 = red2[0][p] + red2[1][p] + red2[2][p] + red2[3][p];
        float u   = s1 * (1.0f / 128.0f);
        float var = fmaxf((s2 - s1 * u) * (1.0f / 127.0f), 0.0f);
        float se  = sqrtf(var) + EPS;
        float iv  = 1.0f / se;
        if (q == 0) {                       // wave-uniform branch (tid < 128)
            u_s[p]  = u;
            se_s[p] = se;
        }
        char* tb = (char*)bufT;
        const int rowoff = p * 256;         // 128 ushort per row
        const int swz    = (p & 15) << 4;
        #pragma unroll
        for (int o8 = 0; o8 < 4; ++o8) {
            float n0 = (v[o8 * 8 + 0] - u) * iv;
            float n1 = (v[o8 * 8 + 1] - u) * iv;
            float n2 = (v[o8 * 8 + 2] - u) * iv;
            float n3 = (v[o8 * 8 + 3] - u) * iv;
            float n4 = (v[o8 * 8 + 4] - u) * iv;
            float n5 = (v[o8 * 8 + 5] - u) * iv;
            float n6 = (v[o8 * 8 + 6] - u) * iv;
            float n7 = (v[o8 * 8 + 7] - u) * iv;
            uint4 d;
            d.x = pack2(n0, n1);
            d.y = pack2(n2, n3);
            d.z = pack2(n4, n5);
            d.w = pack2(n6, n7);
            int byte = (rowoff + (q * 4 + o8) * 16) ^ swz;
            *reinterpret_cast<uint4*>(tb + byte) = d;
        }
    }
    __syncthreads();

    // ---- Phase 4: MFMA conv + epilogue. Wave wv: 16 o x 128 px (8 tiles x 4 K-steps) ----
    {
        const char* tb = (const char*)bufT;
        const int pcol = l & 15;
        const int koff = (l >> 4) << 4;
        const int swz  = pcol << 4;
        float* outp = out + base;
        #pragma unroll
        for (int pt = 0; pt < 8; ++pt) {
            const int pp     = (pt << 4) + pcol;
            const int rowoff = pp * 256;
            f32x4 acc = binit;
            #pragma unroll
            for (int kk = 0; kk < 4; ++kk) {
                int byte = (rowoff + kk * 64 + koff) ^ swz;
                bf16x8 bfrag = *reinterpret_cast<const bf16x8*>(tb + byte);
                acc = __builtin_amdgcn_mfma_f32_16x16x32_bf16(afrag[kk], bfrag, acc, 0, 0, 0);
            }
            const float uu = u_s[pp];
            const float se = se_s[pp];
            int nbyte = (rowoff + od * 2) ^ swz;
            uint2 nn = *reinterpret_cast<const uint2*>(tb + nbyte);
            float x0 = fmaf(bf2f((unsigned short)(nn.x & 0xffffu)), se, uu);
            float x1 = fmaf(bf2f((unsigned short)(nn.x >> 16)),     se, uu);
            float x2 = fmaf(bf2f((unsigned short)(nn.y & 0xffffu)), se, uu);
            float x3 = fmaf(bf2f((unsigned short)(nn.y >> 16)),     se, uu);
            outp[(od + 0) * HW + pp] = x0 * acc[0];
            outp[(od + 1) * HW + pp] = x1 * acc[1];
            outp[(od + 2) * HW + pp] = x2 * acc[2];
            outp[(od + 3) * HW + pp] = x3 * acc[3];
        }
    }
}

extern "C" void kernel_launch(void* const* d_in, const int* in_sizes, int n_in,
                              void* d_out, int out_size, void* d_ws, size_t ws_size,
                              hipStream_t stream) {
    const float* x = (const float*)d_in[0];
    const float* W = (const float*)d_in[1];
    const float* b = (const float*)d_in[2];
    float* out     = (float*)d_out;

    const int nblk = 8 * HW / TILE;            // 4096 blocks
    spnorm_kernel<<<nblk, NT, 0, stream>>>(x, W, b, out);
}